// Round 19
// baseline (429.624 us; speedup 1.0000x reference)
//
#include <hip/hip_runtime.h>
#include <cstdint>
#include <cstddef>

#define BB 32
#define NN 24564
#define CC 81
#define CM1 80
#define KTOP 100
#define MAXDET 100
#define CBINS 28          // selection bins over (0.0078, 1]
#define CSHIFT 21
#define BASEBITS 0x3C000000u
#define SPECBITS 0x3D400000u   // 0.046875f boundary
#define SPECPF   0.0468281f    // SPEC * 0.999 proxy prefilter (rcp err ~3e-7)
#define CAP2 2048
#define CAPB 25           // per-block per-class spec buffer
#define BPI 96            // blocks per image, 256 rows each
#define CAPS 1024         // nms compacted-selection capacity
#define FCH 8
#define FCHN 1000
#define FPAD 1024
#define NCAND (CM1 * KTOP)   // 8000

typedef unsigned long long ull;
typedef unsigned int uint;
typedef float floatx4 __attribute__((ext_vector_type(4)));
typedef floatx4 uf4 __attribute__((aligned(4)));   // rows are only 4B-aligned

// ---- pass 0: zero ccnt/ovf/done (5152 words) ----
__global__ __launch_bounds__(256) void zero_kernel(uint* __restrict__ p, int nwords) {
    int i = blockIdx.x * 256 + threadIdx.x;
    if (i < nwords) p[i] = 0u;
}

__device__ __forceinline__ void bitonic_sort256(ull* a, int S, int tid) {
    for (int k = 2; k <= S; k <<= 1) {
        for (int j = k >> 1; j > 0; j >>= 1) {
            for (int i = tid; i < S; i += 256) {
                int ixj = i ^ j;
                if (ixj > i) {
                    ull x = a[i], y = a[ixj];
                    bool up = ((i & k) == 0);
                    if ((x > y) == up) { a[i] = y; a[ixj] = x; }
                }
            }
            __syncthreads();
        }
    }
}

// ---- pass 1: single-read register rows; exact softmax stats; spec collect ----
__global__ __launch_bounds__(256) void softmax_spec_kernel(const float* __restrict__ conf,
                                                           float2* __restrict__ mxs,
                                                           ull* __restrict__ cand,
                                                           uint* __restrict__ ccnt,
                                                           uint* __restrict__ ovf) {
    __shared__ ull  sbuf[CM1 * CAPB];    // 16000 B
    __shared__ uint scnt[CM1];           // spec counts per class (this block)
    int tid = threadIdx.x;
    if (tid < CM1) scnt[tid] = 0u;
    __syncthreads();

    int b = blockIdx.x / BPI, j = blockIdx.x % BPI;
    int n = j * 256 + tid;
    if (n < NN) {
        const float* row = conf + ((size_t)b * NN + n) * CC;
        const uf4* row4 = reinterpret_cast<const uf4*>(row);
        float r[CC];
        #pragma unroll
        for (int q = 0; q < 20; ++q) {
            floatx4 v = row4[q];
            r[4 * q] = v.x; r[4 * q + 1] = v.y; r[4 * q + 2] = v.z; r[4 * q + 3] = v.w;
        }
        r[80] = row[80];

        float mx = r[0];
        #pragma unroll
        for (int c = 1; c < CC; ++c) mx = fmaxf(mx, r[c]);   // max: order-independent, exact

        float s = 0.f;                                        // exact sequential sum, c = 0..80
        #pragma unroll
        for (int c = 0; c < CC; ++c) {
            r[c] = expf(__fsub_rn(r[c], mx));
            s = __fadd_rn(s, r[c]);
        }
        mxs[(size_t)b * NN + n] = make_float2(mx, s);

        float rcp = __builtin_amdgcn_rcpf(s);
        uint nn = (uint)n;
        #pragma unroll
        for (int c = 1; c < CC; ++c) {
            float p = __fmul_rn(r[c], rcp);
            if (p > SPECPF) {                      // ~1.5% of elements
                float sc = __fdiv_rn(r[c], s);     // exact score bits
                uint eb = __float_as_uint(sc);
                if (eb >= SPECBITS) {
                    uint pp = atomicAdd(&scnt[c - 1], 1u);
                    if (pp < CAPB) sbuf[(c - 1) * CAPB + pp] = (((ull)(~eb)) << 32) | nn;
                }
            }
        }
    }
    __syncthreads();

    // flush spec buffers: one global atomic per class per block, then coalesced copy
    if (tid < CM1) {
        uint c2 = scnt[tid];
        if (c2) {
            int bc = b * CM1 + tid;
            uint nstore = c2 > CAPB ? CAPB : c2;
            uint base = atomicAdd(ccnt + bc, nstore);
            if (c2 > CAPB || base + nstore > CAP2) ovf[bc] = 1u;
            uint lim = base + nstore; if (lim > CAP2) lim = CAP2;
            for (uint i = 0; base + i < lim; ++i)
                cand[(size_t)bc * CAP2 + base + i] = sbuf[tid * CAPB + i];
        }
    }
}

// ---- pass 2: per-(b,c) NMS (inline flag + inline exact fallback) + fused per-image final top-100 ----
__global__ __launch_bounds__(256) void nms_kernel(const ull* __restrict__ cand,
                                                  const uint* __restrict__ ccnt,
                                                  const uint* __restrict__ ovf,
                                                  const float* __restrict__ conf,
                                                  const float2* __restrict__ mxs,
                                                  const float* __restrict__ loc,
                                                  const float* __restrict__ priors,
                                                  float* __restrict__ nms_scores,
                                                  float* __restrict__ nms_boxes,
                                                  uint* __restrict__ done,
                                                  float* __restrict__ out) {
    int bc = blockIdx.x;
    int bimg = bc / CM1, ccls = bc % CM1;
    __shared__ ull arr[CAP2];                 // 16 KB
    __shared__ ull arr2[CAPS];                // 8 KB
    __shared__ uint hist[CBINS];
    __shared__ uint s_cut, s_mode, s_cnt2, s_nz, s_last;
    __shared__ float bx[KTOP][4];
    __shared__ float sv[KTOP];
    __shared__ ull mlo[KTOP], mhi[KTOP];
    __shared__ ull keeplo, keephi;

    int tid = threadIdx.x;
    for (int i = tid; i < CBINS; i += 256) hist[i] = 0u;
    if (tid == 0) { s_cut = 0u; s_mode = 0u; s_cnt2 = 0u; }
    __syncthreads();

    uint rawcnt = ccnt[bc];
    bool flagged = !(ovf[bc] == 0u && rawcnt >= (uint)KTOP);
    int scc; ull* sorted;

    if (!flagged) {
        // ---- common path: load spec list, histogram, rank-Kt cut, compact ----
        int cc = (int)rawcnt; if (cc > CAP2) cc = CAP2;
        const ull* crow = cand + (size_t)bc * CAP2;
        for (int i = tid; i < cc; i += 256) {
            ull k = crow[i];
            arr[i] = k;
            uint bits = ~(uint)(k >> 32);
            uint bin = (bits - BASEBITS) >> CSHIFT;
            if (bin >= CBINS) bin = CBINS - 1;
            atomicAdd(&hist[bin], 1u);
        }
        __syncthreads();
        if (tid == 0) {
            uint Kt = (uint)(cc < KTOP ? cc : KTOP);
            if (Kt > 0) {
                uint cum = 0; int bb2 = 0;
                for (int i = CBINS - 1; i >= 0; --i) {
                    cum += hist[i];
                    if (cum >= Kt) { bb2 = i; break; }
                }
                if (cum <= CAPS) {
                    s_cut = BASEBITS + ((uint)bb2 << CSHIFT);
                    s_mode = 1u;
                }
            }
        }
        __syncthreads();
        if (s_mode) {
            uint cutv = s_cut;
            for (int i = tid; i < cc; i += 256) {
                ull k = arr[i];
                uint bits = ~(uint)(k >> 32);
                if (bits >= cutv) { uint p = atomicAdd(&s_cnt2, 1u); arr2[p] = k; }
            }
            __syncthreads();
            scc = (int)s_cnt2;
            sorted = arr2;
        } else {
            scc = cc;
            sorted = arr;
        }
    } else {
        // ---- rare path: exact self-contained column rescan ----
        int c = ccls + 1;
        for (int n = tid; n < NN; n += 256) {
            float x = conf[((size_t)bimg * NN + n) * CC + c];
            float2 ms = mxs[(size_t)bimg * NN + n];
            float e = expf(__fsub_rn(x, ms.x));
            float sc = __fdiv_rn(e, ms.y);
            if (sc > 0.01f) {
                uint bits = __float_as_uint(sc);
                uint bin = (bits - BASEBITS) >> CSHIFT;
                if (bin >= CBINS) bin = CBINS - 1;
                atomicAdd(&hist[bin], 1u);
            }
        }
        __syncthreads();
        if (tid == 0) {
            uint total = 0;
            for (int i = 0; i < CBINS; ++i) total += hist[i];
            uint Kt = total < KTOP ? total : KTOP;
            s_cut = 0xFFFFFFFFu;
            if (Kt > 0) {
                uint cum = 0; int bb2 = 0;
                for (int i = CBINS - 1; i >= 0; --i) {
                    cum += hist[i];
                    if (cum >= Kt) { bb2 = i; break; }
                }
                uint cutbin = (cum <= CAP2) ? (uint)bb2 : (uint)(bb2 + 1);
                s_cut = BASEBITS + (cutbin << CSHIFT);
            }
        }
        __syncthreads();
        uint cutv = s_cut;
        for (int n = tid; n < NN; n += 256) {
            float x = conf[((size_t)bimg * NN + n) * CC + c];
            float2 ms = mxs[(size_t)bimg * NN + n];
            float e = expf(__fsub_rn(x, ms.x));
            float sc = __fdiv_rn(e, ms.y);
            if (sc > 0.01f) {
                uint bits = __float_as_uint(sc);
                if (bits >= cutv) {
                    uint p = atomicAdd(&s_cnt2, 1u);
                    if (p < CAP2) arr[p] = (((ull)(~bits)) << 32) | (uint)n;
                }
            }
        }
        __syncthreads();
        scc = (int)s_cnt2; if (scc > CAP2) scc = CAP2;
        sorted = arr;
    }

    int S = 1; while (S < scc) S <<= 1; if (S < 2) S = 2;
    for (int i = scc + tid; i < S; i += 256) sorted[i] = ~0ull;
    __syncthreads();
    bitonic_sort256(sorted, S, tid);

    if (tid < KTOP) {
        float val = 0.f; uint n = 0;
        if (tid < scc) {
            ull kk = sorted[tid];
            val = __uint_as_float(~(uint)(kk >> 32));
            n = (uint)(kk & 0xFFFFFFFFu);
        }
        sv[tid] = val;
        float4 l = reinterpret_cast<const float4*>(loc)[(size_t)bimg * NN + n];
        float4 p = reinterpret_cast<const float4*>(priors)[n];
        float cx = __fadd_rn(__fmul_rn(__fmul_rn(l.x, 0.1f), p.z), p.x);
        float cy = __fadd_rn(__fmul_rn(__fmul_rn(l.y, 0.1f), p.w), p.y);
        float w  = __fmul_rn(expf(__fmul_rn(l.z, 0.2f)), p.z);
        float h  = __fmul_rn(expf(__fmul_rn(l.w, 0.2f)), p.w);
        bx[tid][0] = __fsub_rn(cx, __fmul_rn(w, 0.5f));
        bx[tid][1] = __fsub_rn(cy, __fmul_rn(h, 0.5f));
        bx[tid][2] = __fadd_rn(cx, __fmul_rn(w, 0.5f));
        bx[tid][3] = __fadd_rn(cy, __fmul_rn(h, 0.5f));
    }
    __syncthreads();

    if (tid < KTOP) {
        float x1 = bx[tid][0], y1 = bx[tid][1], x2 = bx[tid][2], y2 = bx[tid][3];
        float ai = __fmul_rn(fmaxf(__fsub_rn(x2, x1), 0.f), fmaxf(__fsub_rn(y2, y1), 0.f));
        ull lo = 0, hi = 0;
        for (int jj = 0; jj < KTOP; ++jj) {
            float jx1 = bx[jj][0], jy1 = bx[jj][1], jx2 = bx[jj][2], jy2 = bx[jj][3];
            float iw = fmaxf(__fsub_rn(fminf(x2, jx2), fmaxf(x1, jx1)), 0.f);
            float ih = fmaxf(__fsub_rn(fminf(y2, jy2), fmaxf(y1, jy1)), 0.f);
            float inter = __fmul_rn(iw, ih);
            float aj = __fmul_rn(fmaxf(__fsub_rn(jx2, jx1), 0.f), fmaxf(__fsub_rn(jy2, jy1), 0.f));
            float denom = __fadd_rn(__fsub_rn(__fadd_rn(ai, aj), inter), 1e-8f);
            float iou = __fdiv_rn(inter, denom);
            if (iou > 0.45f) { if (jj < 64) lo |= (1ull << jj); else hi |= (1ull << (jj - 64)); }
        }
        mlo[tid] = lo; mhi[tid] = hi;
    }
    __syncthreads();

    if (tid == 0) {
        ull klo = 0, khi = 0;
        for (int i = 0; i < KTOP; ++i) {
            ull sup = (mlo[i] & klo) | (mhi[i] & khi);
            bool kp = (sv[i] > 0.f) && (sup == 0ull);
            if (kp) { if (i < 64) klo |= (1ull << i); else khi |= (1ull << (i - 64)); }
        }
        keeplo = klo; keephi = khi;
    }
    __syncthreads();

    if (tid < KTOP) {
        bool kp = (tid < 64) ? ((keeplo >> tid) & 1ull) : ((keephi >> (tid - 64)) & 1ull);
        size_t obase = (size_t)bc * KTOP + tid;
        nms_scores[obase] = kp ? sv[tid] : 0.f;
        float4 o; o.x = bx[tid][0]; o.y = bx[tid][1]; o.z = bx[tid][2]; o.w = bx[tid][3];
        reinterpret_cast<float4*>(nms_boxes)[obase] = o;
    }

    // ================= fused per-image final top-100 (last block of each image) =================
    __threadfence();                 // release: make this block's nms outputs device-visible
    __syncthreads();
    if (tid == 0) {
        uint prev = atomicAdd(&done[bimg], 1u);
        s_last = (prev == (uint)(CM1 - 1)) ? 1u : 0u;
    }
    __syncthreads();
    if (!s_last) return;
    __threadfence();                 // acquire: invalidate stale cache before reading peers' data

    const float* srow = nms_scores + (size_t)bimg * NCAND;
    for (int i = tid; i < CBINS; i += 256) hist[i] = 0u;
    if (tid == 0) { s_cut = 0u; s_mode = 0u; s_cnt2 = 0u; s_nz = 0u; }
    __syncthreads();

    uint mynz = 0;
    for (int i = tid; i < NCAND; i += 256) {
        float s = srow[i];
        if (s > 0.f) {
            ++mynz;
            uint bits = __float_as_uint(s);
            uint bin = (bits - BASEBITS) >> CSHIFT;
            if (bin >= CBINS) bin = CBINS - 1;
            atomicAdd(&hist[bin], 1u);
        }
    }
    if (mynz) atomicAdd(&s_nz, mynz);
    __syncthreads();
    if (tid == 0) {
        if (s_nz >= (uint)KTOP) {
            uint cum = 0; int bb2 = 0;
            for (int i = CBINS - 1; i >= 0; --i) {
                cum += hist[i];
                if (cum >= (uint)KTOP) { bb2 = i; break; }
            }
            if (cum <= CAP2) { s_cut = BASEBITS + ((uint)bb2 << CSHIFT); s_mode = 1u; }
        }
    }
    __syncthreads();

    if (s_mode) {
        // fast path: compact nonzero >= cut (>=100 entries, all real), sort, done
        uint cutv = s_cut;
        for (int i = tid; i < NCAND; i += 256) {
            float s = srow[i];
            if (s > 0.f) {
                uint bits = __float_as_uint(s);
                if (bits >= cutv) {
                    uint p = atomicAdd(&s_cnt2, 1u);
                    arr[p] = (((ull)(~bits)) << 32) | (uint)i;
                }
            }
        }
        __syncthreads();
        int fcc = (int)s_cnt2;
        int FS = 1; while (FS < fcc) FS <<= 1; if (FS < 2) FS = 2;
        for (int i = fcc + tid; i < FS; i += 256) arr[i] = ~0ull;
        __syncthreads();
        bitonic_sort256(arr, FS, tid);
    } else {
        // exact slow path (rare): validated two-stage partial+merge, sequential in-block
        for (int ch = 0; ch < FCH; ++ch) {
            for (int i = tid; i < FPAD; i += 256) {
                ull key;
                if (i < FCHN) {
                    float s = srow[ch * FCHN + i];
                    uint bits = (s > 0.f) ? __float_as_uint(s) : 0u;
                    key = (((ull)(~bits)) << 32) | (uint)(ch * FCHN + i);
                } else key = ~0ull;
                arr2[i] = key;
            }
            __syncthreads();
            bitonic_sort256(arr2, FPAD, tid);
            if (tid < KTOP) arr[ch * KTOP + tid] = arr2[tid];
            __syncthreads();
        }
        for (int i = FCH * KTOP + tid; i < FPAD; i += 256) arr[i] = ~0ull;
        __syncthreads();
        bitonic_sort256(arr, FPAD, tid);
    }

    if (tid < MAXDET) {
        ull kk = arr[tid];
        uint hb = (uint)(kk >> 32);
        uint idx = (uint)(kk & 0xFFFFFFFFu);
        float val = __uint_as_float(~hb);     // zeros decode to 0.0f
        float4 b4 = reinterpret_cast<const float4*>(nms_boxes)[(size_t)bimg * NCAND + idx];
        reinterpret_cast<float4*>(out)[(size_t)bimg * MAXDET + tid] = b4;
        out[BB * MAXDET * 4 + bimg * MAXDET + tid] = val;
        out[BB * MAXDET * 5 + bimg * MAXDET + tid] = (float)(idx / KTOP + 1);
    }
}

extern "C" void kernel_launch(void* const* d_in, const int* in_sizes, int n_in,
                              void* d_out, int out_size, void* d_ws, size_t ws_size,
                              hipStream_t stream) {
    const float* loc    = (const float*)d_in[0];
    const float* conf   = (const float*)d_in[1];
    const float* priors = (const float*)d_in[2];
    float* out = (float*)d_out;

    // workspace layout (16B-aligned chunks); ccnt/ovf/done are the zeroed trio (contiguous)
    char* ws = (char*)d_ws;
    float* nms_scores = (float*)ws;                                        // 1.02 MB
    float* nms_boxes  = nms_scores + (size_t)BB * CM1 * KTOP;              // 4.1 MB
    ull*   cand       = (ull*)(nms_boxes + (size_t)BB * CM1 * KTOP * 4);   // 41.9 MB
    float2* mxs       = (float2*)(cand + (size_t)BB * CM1 * CAP2);         // 6.3 MB
    uint*  ccnt       = (uint*)(mxs + (size_t)BB * NN);                    // 2560 zeroed
    uint*  ovf        = ccnt + (size_t)BB * CM1;                           // 2560 zeroed
    uint*  done       = ovf + (size_t)BB * CM1;                            // 32   zeroed

    const int zwords = BB * CM1 * 2 + BB;
    zero_kernel<<<(zwords + 255) / 256, 256, 0, stream>>>(ccnt, zwords);

    softmax_spec_kernel<<<BB * BPI, 256, 0, stream>>>(conf, mxs, cand, ccnt, ovf);
    nms_kernel<<<BB * CM1, 256, 0, stream>>>(cand, ccnt, ovf, conf, mxs, loc, priors,
                                             nms_scores, nms_boxes, done, out);
}

// Round 20
// 234.373 us; speedup vs baseline: 1.8331x; 1.8331x over previous
//
#include <hip/hip_runtime.h>
#include <cstdint>
#include <cstddef>

#define BB 32
#define NN 24564
#define CC 81
#define CM1 80
#define KTOP 100
#define MAXDET 100
#define CBINS 28          // selection bins over (0.0078, 1]
#define CSHIFT 21
#define BASEBITS 0x3C000000u
#define SPECBITS 0x3D400000u   // 0.046875f boundary
#define SPECPF   0.0468281f    // SPEC * 0.999 proxy prefilter (rcp err ~3e-7)
#define CAP2 2048
#define CAPB 25           // per-block per-class spec buffer
#define BPI 96            // blocks per image, 256 rows each
#define CAPS 1024         // nms compacted-selection capacity
#define FCH 8
#define FCHN 1000
#define FPAD 1024
#define NCAND (CM1 * KTOP)   // 8000

typedef unsigned long long ull;
typedef unsigned int uint;
typedef float floatx4 __attribute__((ext_vector_type(4)));
typedef floatx4 uf4 __attribute__((aligned(4)));   // rows are only 4B-aligned

// ---- pass 0: zero ccnt/ovf (5120 words) ----
__global__ __launch_bounds__(256) void zero_kernel(uint* __restrict__ p, int nwords) {
    int i = blockIdx.x * 256 + threadIdx.x;
    if (i < nwords) p[i] = 0u;
}

__device__ __forceinline__ void bitonic_sort256(ull* a, int S, int tid) {
    for (int k = 2; k <= S; k <<= 1) {
        for (int j = k >> 1; j > 0; j >>= 1) {
            for (int i = tid; i < S; i += 256) {
                int ixj = i ^ j;
                if (ixj > i) {
                    ull x = a[i], y = a[ixj];
                    bool up = ((i & k) == 0);
                    if ((x > y) == up) { a[i] = y; a[ixj] = x; }
                }
            }
            __syncthreads();
        }
    }
}

// ---- pass 1: single-read register rows; exact softmax stats; spec collect ----
__global__ __launch_bounds__(256) void softmax_spec_kernel(const float* __restrict__ conf,
                                                           float2* __restrict__ mxs,
                                                           ull* __restrict__ cand,
                                                           uint* __restrict__ ccnt,
                                                           uint* __restrict__ ovf) {
    __shared__ ull  sbuf[CM1 * CAPB];    // 16000 B
    __shared__ uint scnt[CM1];           // spec counts per class (this block)
    int tid = threadIdx.x;
    if (tid < CM1) scnt[tid] = 0u;
    __syncthreads();

    int b = blockIdx.x / BPI, j = blockIdx.x % BPI;
    int n = j * 256 + tid;
    if (n < NN) {
        const float* row = conf + ((size_t)b * NN + n) * CC;
        const uf4* row4 = reinterpret_cast<const uf4*>(row);
        float r[CC];
        #pragma unroll
        for (int q = 0; q < 20; ++q) {
            floatx4 v = row4[q];
            r[4 * q] = v.x; r[4 * q + 1] = v.y; r[4 * q + 2] = v.z; r[4 * q + 3] = v.w;
        }
        r[80] = row[80];

        float mx = r[0];
        #pragma unroll
        for (int c = 1; c < CC; ++c) mx = fmaxf(mx, r[c]);   // max: order-independent, exact

        float s = 0.f;                                        // exact sequential sum, c = 0..80
        #pragma unroll
        for (int c = 0; c < CC; ++c) {
            r[c] = expf(__fsub_rn(r[c], mx));
            s = __fadd_rn(s, r[c]);
        }
        mxs[(size_t)b * NN + n] = make_float2(mx, s);

        float rcp = __builtin_amdgcn_rcpf(s);
        uint nn = (uint)n;
        #pragma unroll
        for (int c = 1; c < CC; ++c) {
            float p = __fmul_rn(r[c], rcp);
            if (p > SPECPF) {                      // ~1.5% of elements
                float sc = __fdiv_rn(r[c], s);     // exact score bits
                uint eb = __float_as_uint(sc);
                if (eb >= SPECBITS) {
                    uint pp = atomicAdd(&scnt[c - 1], 1u);
                    if (pp < CAPB) sbuf[(c - 1) * CAPB + pp] = (((ull)(~eb)) << 32) | nn;
                }
            }
        }
    }
    __syncthreads();

    // flush spec buffers: one global atomic per class per block, then coalesced copy
    if (tid < CM1) {
        uint c2 = scnt[tid];
        if (c2) {
            int bc = b * CM1 + tid;
            uint nstore = c2 > CAPB ? CAPB : c2;
            uint base = atomicAdd(ccnt + bc, nstore);
            if (c2 > CAPB || base + nstore > CAP2) ovf[bc] = 1u;
            uint lim = base + nstore; if (lim > CAP2) lim = CAP2;
            for (uint i = 0; base + i < lim; ++i)
                cand[(size_t)bc * CAP2 + base + i] = sbuf[tid * CAPB + i];
        }
    }
}

// ---- pass 2: per-(b,c) NMS with inline flag + inline exact fallback rescan (R18-identical) ----
__global__ __launch_bounds__(256) void nms_kernel(const ull* __restrict__ cand,
                                                  const uint* __restrict__ ccnt,
                                                  const uint* __restrict__ ovf,
                                                  const float* __restrict__ conf,
                                                  const float2* __restrict__ mxs,
                                                  const float* __restrict__ loc,
                                                  const float* __restrict__ priors,
                                                  float* __restrict__ nms_scores,
                                                  float* __restrict__ nms_boxes) {
    int bc = blockIdx.x;
    int bimg = bc / CM1, ccls = bc % CM1;
    __shared__ ull arr[CAP2];                 // 16 KB
    __shared__ ull arr2[CAPS];                // 8 KB
    __shared__ uint hist[CBINS];
    __shared__ uint s_cut, s_mode, s_cnt2;
    __shared__ float bx[KTOP][4];
    __shared__ float sv[KTOP];
    __shared__ ull mlo[KTOP], mhi[KTOP];
    __shared__ ull keeplo, keephi;

    int tid = threadIdx.x;
    for (int i = tid; i < CBINS; i += 256) hist[i] = 0u;
    if (tid == 0) { s_cut = 0u; s_mode = 0u; s_cnt2 = 0u; }
    __syncthreads();

    uint rawcnt = ccnt[bc];
    bool flagged = !(ovf[bc] == 0u && rawcnt >= (uint)KTOP);
    int scc; ull* sorted;

    if (!flagged) {
        int cc = (int)rawcnt; if (cc > CAP2) cc = CAP2;
        const ull* crow = cand + (size_t)bc * CAP2;
        for (int i = tid; i < cc; i += 256) {
            ull k = crow[i];
            arr[i] = k;
            uint bits = ~(uint)(k >> 32);
            uint bin = (bits - BASEBITS) >> CSHIFT;
            if (bin >= CBINS) bin = CBINS - 1;
            atomicAdd(&hist[bin], 1u);
        }
        __syncthreads();
        if (tid == 0) {
            uint Kt = (uint)(cc < KTOP ? cc : KTOP);
            if (Kt > 0) {
                uint cum = 0; int bb2 = 0;
                for (int i = CBINS - 1; i >= 0; --i) {
                    cum += hist[i];
                    if (cum >= Kt) { bb2 = i; break; }
                }
                if (cum <= CAPS) {
                    s_cut = BASEBITS + ((uint)bb2 << CSHIFT);
                    s_mode = 1u;
                }
            }
        }
        __syncthreads();
        if (s_mode) {
            uint cutv = s_cut;
            for (int i = tid; i < cc; i += 256) {
                ull k = arr[i];
                uint bits = ~(uint)(k >> 32);
                if (bits >= cutv) { uint p = atomicAdd(&s_cnt2, 1u); arr2[p] = k; }
            }
            __syncthreads();
            scc = (int)s_cnt2;
            sorted = arr2;
        } else {
            scc = cc;
            sorted = arr;
        }
    } else {
        int c = ccls + 1;
        for (int n = tid; n < NN; n += 256) {
            float x = conf[((size_t)bimg * NN + n) * CC + c];
            float2 ms = mxs[(size_t)bimg * NN + n];
            float e = expf(__fsub_rn(x, ms.x));
            float sc = __fdiv_rn(e, ms.y);
            if (sc > 0.01f) {
                uint bits = __float_as_uint(sc);
                uint bin = (bits - BASEBITS) >> CSHIFT;
                if (bin >= CBINS) bin = CBINS - 1;
                atomicAdd(&hist[bin], 1u);
            }
        }
        __syncthreads();
        if (tid == 0) {
            uint total = 0;
            for (int i = 0; i < CBINS; ++i) total += hist[i];
            uint Kt = total < KTOP ? total : KTOP;
            s_cut = 0xFFFFFFFFu;
            if (Kt > 0) {
                uint cum = 0; int bb2 = 0;
                for (int i = CBINS - 1; i >= 0; --i) {
                    cum += hist[i];
                    if (cum >= Kt) { bb2 = i; break; }
                }
                uint cutbin = (cum <= CAP2) ? (uint)bb2 : (uint)(bb2 + 1);
                s_cut = BASEBITS + (cutbin << CSHIFT);
            }
        }
        __syncthreads();
        uint cutv = s_cut;
        for (int n = tid; n < NN; n += 256) {
            float x = conf[((size_t)bimg * NN + n) * CC + c];
            float2 ms = mxs[(size_t)bimg * NN + n];
            float e = expf(__fsub_rn(x, ms.x));
            float sc = __fdiv_rn(e, ms.y);
            if (sc > 0.01f) {
                uint bits = __float_as_uint(sc);
                if (bits >= cutv) {
                    uint p = atomicAdd(&s_cnt2, 1u);
                    if (p < CAP2) arr[p] = (((ull)(~bits)) << 32) | (uint)n;
                }
            }
        }
        __syncthreads();
        scc = (int)s_cnt2; if (scc > CAP2) scc = CAP2;
        sorted = arr;
    }

    int S = 1; while (S < scc) S <<= 1; if (S < 2) S = 2;
    for (int i = scc + tid; i < S; i += 256) sorted[i] = ~0ull;
    __syncthreads();
    bitonic_sort256(sorted, S, tid);

    if (tid < KTOP) {
        float val = 0.f; uint n = 0;
        if (tid < scc) {
            ull kk = sorted[tid];
            val = __uint_as_float(~(uint)(kk >> 32));
            n = (uint)(kk & 0xFFFFFFFFu);
        }
        sv[tid] = val;
        float4 l = reinterpret_cast<const float4*>(loc)[(size_t)bimg * NN + n];
        float4 p = reinterpret_cast<const float4*>(priors)[n];
        float cx = __fadd_rn(__fmul_rn(__fmul_rn(l.x, 0.1f), p.z), p.x);
        float cy = __fadd_rn(__fmul_rn(__fmul_rn(l.y, 0.1f), p.w), p.y);
        float w  = __fmul_rn(expf(__fmul_rn(l.z, 0.2f)), p.z);
        float h  = __fmul_rn(expf(__fmul_rn(l.w, 0.2f)), p.w);
        bx[tid][0] = __fsub_rn(cx, __fmul_rn(w, 0.5f));
        bx[tid][1] = __fsub_rn(cy, __fmul_rn(h, 0.5f));
        bx[tid][2] = __fadd_rn(cx, __fmul_rn(w, 0.5f));
        bx[tid][3] = __fadd_rn(cy, __fmul_rn(h, 0.5f));
    }
    __syncthreads();

    if (tid < KTOP) {
        float x1 = bx[tid][0], y1 = bx[tid][1], x2 = bx[tid][2], y2 = bx[tid][3];
        float ai = __fmul_rn(fmaxf(__fsub_rn(x2, x1), 0.f), fmaxf(__fsub_rn(y2, y1), 0.f));
        ull lo = 0, hi = 0;
        for (int jj = 0; jj < KTOP; ++jj) {
            float jx1 = bx[jj][0], jy1 = bx[jj][1], jx2 = bx[jj][2], jy2 = bx[jj][3];
            float iw = fmaxf(__fsub_rn(fminf(x2, jx2), fmaxf(x1, jx1)), 0.f);
            float ih = fmaxf(__fsub_rn(fminf(y2, jy2), fmaxf(y1, jy1)), 0.f);
            float inter = __fmul_rn(iw, ih);
            float aj = __fmul_rn(fmaxf(__fsub_rn(jx2, jx1), 0.f), fmaxf(__fsub_rn(jy2, jy1), 0.f));
            float denom = __fadd_rn(__fsub_rn(__fadd_rn(ai, aj), inter), 1e-8f);
            float iou = __fdiv_rn(inter, denom);
            if (iou > 0.45f) { if (jj < 64) lo |= (1ull << jj); else hi |= (1ull << (jj - 64)); }
        }
        mlo[tid] = lo; mhi[tid] = hi;
    }
    __syncthreads();

    if (tid == 0) {
        ull klo = 0, khi = 0;
        for (int i = 0; i < KTOP; ++i) {
            ull sup = (mlo[i] & klo) | (mhi[i] & khi);
            bool kp = (sv[i] > 0.f) && (sup == 0ull);
            if (kp) { if (i < 64) klo |= (1ull << i); else khi |= (1ull << (i - 64)); }
        }
        keeplo = klo; keephi = khi;
    }
    __syncthreads();

    if (tid < KTOP) {
        bool kp = (tid < 64) ? ((keeplo >> tid) & 1ull) : ((keephi >> (tid - 64)) & 1ull);
        size_t obase = (size_t)bc * KTOP + tid;
        nms_scores[obase] = kp ? sv[tid] : 0.f;
        float4 o; o.x = bx[tid][0]; o.y = bx[tid][1]; o.z = bx[tid][2]; o.w = bx[tid][3];
        reinterpret_cast<float4*>(nms_boxes)[obase] = o;
    }
}

// ---- pass 3: per-image final top-100 in ONE kernel (hist-cut fast path; exact slow path) ----
__global__ __launch_bounds__(256) void final_topk_kernel(const float* __restrict__ nms_scores,
                                                         const float* __restrict__ nms_boxes,
                                                         float* __restrict__ out) {
    int b = blockIdx.x;
    __shared__ ull arr[CAP2];                 // 16 KB
    __shared__ ull arr2[FPAD];                // 8 KB
    __shared__ uint hist[CBINS];
    __shared__ uint s_cut, s_mode, s_cnt2, s_nz;
    int tid = threadIdx.x;

    const float* srow = nms_scores + (size_t)b * NCAND;
    for (int i = tid; i < CBINS; i += 256) hist[i] = 0u;
    if (tid == 0) { s_cut = 0u; s_mode = 0u; s_cnt2 = 0u; s_nz = 0u; }
    __syncthreads();

    uint mynz = 0;
    for (int i = tid; i < NCAND; i += 256) {
        float s = srow[i];
        if (s > 0.f) {
            ++mynz;
            uint bits = __float_as_uint(s);
            uint bin = (bits - BASEBITS) >> CSHIFT;
            if (bin >= CBINS) bin = CBINS - 1;
            atomicAdd(&hist[bin], 1u);
        }
    }
    if (mynz) atomicAdd(&s_nz, mynz);
    __syncthreads();
    if (tid == 0) {
        if (s_nz >= (uint)KTOP) {
            uint cum = 0; int bb2 = 0;
            for (int i = CBINS - 1; i >= 0; --i) {
                cum += hist[i];
                if (cum >= (uint)KTOP) { bb2 = i; break; }
            }
            if (cum <= CAP2) { s_cut = BASEBITS + ((uint)bb2 << CSHIFT); s_mode = 1u; }
        }
    }
    __syncthreads();

    if (s_mode) {
        // fast path: all top-100 have score >= cut; compact + sort (>=100 real entries)
        uint cutv = s_cut;
        for (int i = tid; i < NCAND; i += 256) {
            float s = srow[i];
            if (s > 0.f) {
                uint bits = __float_as_uint(s);
                if (bits >= cutv) {
                    uint p = atomicAdd(&s_cnt2, 1u);
                    arr[p] = (((ull)(~bits)) << 32) | (uint)i;
                }
            }
        }
        __syncthreads();
        int fcc = (int)s_cnt2;
        int FS = 1; while (FS < fcc) FS <<= 1; if (FS < 2) FS = 2;
        for (int i = fcc + tid; i < FS; i += 256) arr[i] = ~0ull;
        __syncthreads();
        bitonic_sort256(arr, FS, tid);
    } else {
        // exact slow path (rare): two-stage partial+merge sequential in-block (R19-validated)
        for (int ch = 0; ch < FCH; ++ch) {
            for (int i = tid; i < FPAD; i += 256) {
                ull key;
                if (i < FCHN) {
                    float s = srow[ch * FCHN + i];
                    uint bits = (s > 0.f) ? __float_as_uint(s) : 0u;
                    key = (((ull)(~bits)) << 32) | (uint)(ch * FCHN + i);
                } else key = ~0ull;
                arr2[i] = key;
            }
            __syncthreads();
            bitonic_sort256(arr2, FPAD, tid);
            if (tid < KTOP) arr[ch * KTOP + tid] = arr2[tid];
            __syncthreads();
        }
        for (int i = FCH * KTOP + tid; i < FPAD; i += 256) arr[i] = ~0ull;
        __syncthreads();
        bitonic_sort256(arr, FPAD, tid);
    }

    if (tid < MAXDET) {
        ull kk = arr[tid];
        uint hb = (uint)(kk >> 32);
        uint idx = (uint)(kk & 0xFFFFFFFFu);
        float val = __uint_as_float(~hb);     // zeros decode to 0.0f
        float4 b4 = reinterpret_cast<const float4*>(nms_boxes)[(size_t)b * NCAND + idx];
        reinterpret_cast<float4*>(out)[(size_t)b * MAXDET + tid] = b4;
        out[BB * MAXDET * 4 + b * MAXDET + tid] = val;
        out[BB * MAXDET * 5 + b * MAXDET + tid] = (float)(idx / KTOP + 1);
    }
}

extern "C" void kernel_launch(void* const* d_in, const int* in_sizes, int n_in,
                              void* d_out, int out_size, void* d_ws, size_t ws_size,
                              hipStream_t stream) {
    const float* loc    = (const float*)d_in[0];
    const float* conf   = (const float*)d_in[1];
    const float* priors = (const float*)d_in[2];
    float* out = (float*)d_out;

    // workspace layout (16B-aligned chunks); ccnt/ovf are the zeroed pair (contiguous)
    char* ws = (char*)d_ws;
    float* nms_scores = (float*)ws;                                        // 1.02 MB
    float* nms_boxes  = nms_scores + (size_t)BB * CM1 * KTOP;              // 4.1 MB
    ull*   cand       = (ull*)(nms_boxes + (size_t)BB * CM1 * KTOP * 4);   // 41.9 MB
    float2* mxs       = (float2*)(cand + (size_t)BB * CM1 * CAP2);         // 6.3 MB
    uint*  ccnt       = (uint*)(mxs + (size_t)BB * NN);                    // 2560 zeroed
    uint*  ovf        = ccnt + (size_t)BB * CM1;                           // 2560 zeroed

    zero_kernel<<<(BB * CM1 * 2 + 255) / 256, 256, 0, stream>>>(ccnt, BB * CM1 * 2);

    softmax_spec_kernel<<<BB * BPI, 256, 0, stream>>>(conf, mxs, cand, ccnt, ovf);
    nms_kernel<<<BB * CM1, 256, 0, stream>>>(cand, ccnt, ovf, conf, mxs, loc, priors,
                                             nms_scores, nms_boxes);
    final_topk_kernel<<<BB, 256, 0, stream>>>(nms_scores, nms_boxes, out);
}

// Round 21
// 232.632 us; speedup vs baseline: 1.8468x; 1.0075x over previous
//
#include <hip/hip_runtime.h>
#include <cstdint>
#include <cstddef>

#define BB 32
#define NN 24564
#define CC 81
#define CM1 80
#define KTOP 100
#define MAXDET 100
#define CBINS 28          // selection bins over (0.0078, 1]
#define CSHIFT 21
#define BASEBITS 0x3C000000u
#define SPECBITS 0x3D400000u   // 0.046875f boundary
#define SPECPF   0.0468281f    // SPEC * 0.999 proxy prefilter (rcp err ~3e-7)
#define CAP2 2048
#define CAPB 25           // per-block per-class spec buffer
#define BPI 96            // blocks per image, 256 rows each
#define FCH 8
#define FCHN 1000
#define FPAD 1024
#define NCAND (CM1 * KTOP)   // 8000

typedef unsigned long long ull;
typedef unsigned int uint;
typedef float floatx4 __attribute__((ext_vector_type(4)));
typedef floatx4 uf4 __attribute__((aligned(4)));   // rows are only 4B-aligned

// ---- pass 0: zero ccnt/ovf (5120 words) ----
__global__ __launch_bounds__(256) void zero_kernel(uint* __restrict__ p, int nwords) {
    int i = blockIdx.x * 256 + threadIdx.x;
    if (i < nwords) p[i] = 0u;
}

__device__ __forceinline__ void bitonic_sort256(ull* a, int S, int tid) {
    for (int k = 2; k <= S; k <<= 1) {
        for (int j = k >> 1; j > 0; j >>= 1) {
            for (int i = tid; i < S; i += 256) {
                int ixj = i ^ j;
                if (ixj > i) {
                    ull x = a[i], y = a[ixj];
                    bool up = ((i & k) == 0);
                    if ((x > y) == up) { a[i] = y; a[ixj] = x; }
                }
            }
            __syncthreads();
        }
    }
}

// ---- pass 1: single-read register rows; exact softmax stats; spec collect ----
__global__ __launch_bounds__(256) void softmax_spec_kernel(const float* __restrict__ conf,
                                                           float2* __restrict__ mxs,
                                                           ull* __restrict__ cand,
                                                           uint* __restrict__ ccnt,
                                                           uint* __restrict__ ovf) {
    __shared__ ull  sbuf[CM1 * CAPB];    // 16000 B
    __shared__ uint scnt[CM1];           // spec counts per class (this block)
    int tid = threadIdx.x;
    if (tid < CM1) scnt[tid] = 0u;
    __syncthreads();

    int b = blockIdx.x / BPI, j = blockIdx.x % BPI;
    int n = j * 256 + tid;
    if (n < NN) {
        const float* row = conf + ((size_t)b * NN + n) * CC;
        const uf4* row4 = reinterpret_cast<const uf4*>(row);
        float r[CC];
        #pragma unroll
        for (int q = 0; q < 20; ++q) {
            floatx4 v = row4[q];
            r[4 * q] = v.x; r[4 * q + 1] = v.y; r[4 * q + 2] = v.z; r[4 * q + 3] = v.w;
        }
        r[80] = row[80];

        float mx = r[0];
        #pragma unroll
        for (int c = 1; c < CC; ++c) mx = fmaxf(mx, r[c]);   // max: order-independent, exact

        float s = 0.f;                                        // exact sequential sum, c = 0..80
        #pragma unroll
        for (int c = 0; c < CC; ++c) {
            r[c] = expf(__fsub_rn(r[c], mx));
            s = __fadd_rn(s, r[c]);
        }
        mxs[(size_t)b * NN + n] = make_float2(mx, s);

        float rcp = __builtin_amdgcn_rcpf(s);
        uint nn = (uint)n;
        #pragma unroll
        for (int c = 1; c < CC; ++c) {
            float p = __fmul_rn(r[c], rcp);
            if (p > SPECPF) {                      // ~1.5% of elements
                float sc = __fdiv_rn(r[c], s);     // exact score bits
                uint eb = __float_as_uint(sc);
                if (eb >= SPECBITS) {
                    uint pp = atomicAdd(&scnt[c - 1], 1u);
                    if (pp < CAPB) sbuf[(c - 1) * CAPB + pp] = (((ull)(~eb)) << 32) | nn;
                }
            }
        }
    }
    __syncthreads();

    // flush spec buffers: one global atomic per class per block, then coalesced copy
    if (tid < CM1) {
        uint c2 = scnt[tid];
        if (c2) {
            int bc = b * CM1 + tid;
            uint nstore = c2 > CAPB ? CAPB : c2;
            uint base = atomicAdd(ccnt + bc, nstore);
            if (c2 > CAPB || base + nstore > CAP2) ovf[bc] = 1u;
            uint lim = base + nstore; if (lim > CAP2) lim = CAP2;
            for (uint i = 0; base + i < lim; ++i)
                cand[(size_t)bc * CAP2 + base + i] = sbuf[tid * CAPB + i];
        }
    }
}

// ---- pass 2: per-(b,c) NMS: hist/cut from global, compact to LDS, RANK-BY-COUNT top-100 ----
__global__ __launch_bounds__(256) void nms_kernel(const ull* __restrict__ cand,
                                                  const uint* __restrict__ ccnt,
                                                  const uint* __restrict__ ovf,
                                                  const float* __restrict__ conf,
                                                  const float2* __restrict__ mxs,
                                                  const float* __restrict__ loc,
                                                  const float* __restrict__ priors,
                                                  float* __restrict__ nms_scores,
                                                  float* __restrict__ nms_boxes) {
    int bc = blockIdx.x;
    int bimg = bc / CM1, ccls = bc % CM1;
    __shared__ ull arr2[CAP2];                // 16 KB: compacted candidates
    __shared__ ull keysort[KTOP];             // exact top-100 by (score desc, idx asc)
    __shared__ uint hist[CBINS];
    __shared__ uint s_cut, s_cnt2;
    __shared__ float bx[KTOP][4];
    __shared__ float sv[KTOP];
    __shared__ ull mlo[KTOP], mhi[KTOP];
    __shared__ ull keeplo, keephi;

    int tid = threadIdx.x;
    for (int i = tid; i < CBINS; i += 256) hist[i] = 0u;
    if (tid < KTOP) keysort[tid] = ((ull)0xFFFFFFFFu) << 32;   // decodes to val=0, idx=0
    if (tid == 0) { s_cut = 0u; s_cnt2 = 0u; }
    __syncthreads();

    uint rawcnt = ccnt[bc];
    bool flagged = !(ovf[bc] == 0u && rawcnt >= (uint)KTOP);

    if (!flagged) {
        // ---- common path: hist over global cand row, rank-Kt cut, compact (global->LDS) ----
        int cc = (int)rawcnt; if (cc > CAP2) cc = CAP2;
        const ull* crow = cand + (size_t)bc * CAP2;
        for (int i = tid; i < cc; i += 256) {
            uint bits = ~(uint)(crow[i] >> 32);
            uint bin = (bits - BASEBITS) >> CSHIFT;
            if (bin >= CBINS) bin = CBINS - 1;
            atomicAdd(&hist[bin], 1u);
        }
        __syncthreads();
        if (tid == 0) {
            uint Kt = (uint)(cc < KTOP ? cc : KTOP);   // Kt >= 100 here (rawcnt >= 100)
            uint cum = 0; int bb2 = 0;
            for (int i = CBINS - 1; i >= 0; --i) {
                cum += hist[i];
                if (cum >= Kt) { bb2 = i; break; }
            }
            // cum <= cc <= CAP2 always: compaction always fits
            s_cut = BASEBITS + ((uint)bb2 << CSHIFT);
        }
        __syncthreads();
        uint cutv = s_cut;
        for (int i = tid; i < cc; i += 256) {
            ull k = crow[i];                           // L2-resident re-read
            uint bits = ~(uint)(k >> 32);
            if (bits >= cutv) { uint p = atomicAdd(&s_cnt2, 1u); arr2[p] = k; }
        }
        __syncthreads();
    } else {
        // ---- rare path: exact self-contained column rescan (validated logic) ----
        int c = ccls + 1;
        for (int n = tid; n < NN; n += 256) {
            float x = conf[((size_t)bimg * NN + n) * CC + c];
            float2 ms = mxs[(size_t)bimg * NN + n];
            float e = expf(__fsub_rn(x, ms.x));
            float sc = __fdiv_rn(e, ms.y);
            if (sc > 0.01f) {
                uint bits = __float_as_uint(sc);
                uint bin = (bits - BASEBITS) >> CSHIFT;
                if (bin >= CBINS) bin = CBINS - 1;
                atomicAdd(&hist[bin], 1u);
            }
        }
        __syncthreads();
        if (tid == 0) {
            uint total = 0;
            for (int i = 0; i < CBINS; ++i) total += hist[i];
            uint Kt = total < KTOP ? total : KTOP;
            s_cut = 0xFFFFFFFFu;
            if (Kt > 0) {
                uint cum = 0; int bb2 = 0;
                for (int i = CBINS - 1; i >= 0; --i) {
                    cum += hist[i];
                    if (cum >= Kt) { bb2 = i; break; }
                }
                uint cutbin = (cum <= CAP2) ? (uint)bb2 : (uint)(bb2 + 1);
                s_cut = BASEBITS + (cutbin << CSHIFT);
            }
        }
        __syncthreads();
        uint cutv = s_cut;
        for (int n = tid; n < NN; n += 256) {
            float x = conf[((size_t)bimg * NN + n) * CC + c];
            float2 ms = mxs[(size_t)bimg * NN + n];
            float e = expf(__fsub_rn(x, ms.x));
            float sc = __fdiv_rn(e, ms.y);
            if (sc > 0.01f) {
                uint bits = __float_as_uint(sc);
                if (bits >= cutv) {
                    uint p = atomicAdd(&s_cnt2, 1u);
                    if (p < CAP2) arr2[p] = (((ull)(~bits)) << 32) | (uint)n;
                }
            }
        }
        __syncthreads();
    }

    int scc = (int)s_cnt2; if (scc > CAP2) scc = CAP2;

    // ---- exact rank-by-count selection (keys unique): 0 extra barriers, no LDS swaps ----
    {
        ull myk[8]; int rnk[8];
        #pragma unroll
        for (int t = 0; t < 8; ++t) {
            int i = tid + t * 256;
            myk[t] = (i < scc) ? arr2[i] : ~0ull;
            rnk[t] = 0;
        }
        for (int j = 0; j < scc; ++j) {
            ull kj = arr2[j];                          // broadcast LDS read
            #pragma unroll
            for (int t = 0; t < 8; ++t) rnk[t] += (kj < myk[t]) ? 1 : 0;
        }
        #pragma unroll
        for (int t = 0; t < 8; ++t) {
            int i = tid + t * 256;
            if (i < scc && rnk[t] < KTOP) keysort[rnk[t]] = myk[t];
        }
    }
    __syncthreads();

    if (tid < KTOP) {
        ull kk = keysort[tid];
        float val = __uint_as_float(~(uint)(kk >> 32));  // empty slots -> 0.0f
        uint n = (uint)(kk & 0xFFFFFFFFu);
        sv[tid] = val;
        float4 l = reinterpret_cast<const float4*>(loc)[(size_t)bimg * NN + n];
        float4 p = reinterpret_cast<const float4*>(priors)[n];
        float cx = __fadd_rn(__fmul_rn(__fmul_rn(l.x, 0.1f), p.z), p.x);
        float cy = __fadd_rn(__fmul_rn(__fmul_rn(l.y, 0.1f), p.w), p.y);
        float w  = __fmul_rn(expf(__fmul_rn(l.z, 0.2f)), p.z);
        float h  = __fmul_rn(expf(__fmul_rn(l.w, 0.2f)), p.w);
        bx[tid][0] = __fsub_rn(cx, __fmul_rn(w, 0.5f));
        bx[tid][1] = __fsub_rn(cy, __fmul_rn(h, 0.5f));
        bx[tid][2] = __fadd_rn(cx, __fmul_rn(w, 0.5f));
        bx[tid][3] = __fadd_rn(cy, __fmul_rn(h, 0.5f));
    }
    __syncthreads();

    if (tid < KTOP) {
        float x1 = bx[tid][0], y1 = bx[tid][1], x2 = bx[tid][2], y2 = bx[tid][3];
        float ai = __fmul_rn(fmaxf(__fsub_rn(x2, x1), 0.f), fmaxf(__fsub_rn(y2, y1), 0.f));
        ull lo = 0, hi = 0;
        for (int jj = 0; jj < KTOP; ++jj) {
            float jx1 = bx[jj][0], jy1 = bx[jj][1], jx2 = bx[jj][2], jy2 = bx[jj][3];
            float iw = fmaxf(__fsub_rn(fminf(x2, jx2), fmaxf(x1, jx1)), 0.f);
            float ih = fmaxf(__fsub_rn(fminf(y2, jy2), fmaxf(y1, jy1)), 0.f);
            float inter = __fmul_rn(iw, ih);
            float aj = __fmul_rn(fmaxf(__fsub_rn(jx2, jx1), 0.f), fmaxf(__fsub_rn(jy2, jy1), 0.f));
            float denom = __fadd_rn(__fsub_rn(__fadd_rn(ai, aj), inter), 1e-8f);
            float iou = __fdiv_rn(inter, denom);
            if (iou > 0.45f) { if (jj < 64) lo |= (1ull << jj); else hi |= (1ull << (jj - 64)); }
        }
        mlo[tid] = lo; mhi[tid] = hi;
    }
    __syncthreads();

    if (tid == 0) {
        ull klo = 0, khi = 0;
        for (int i = 0; i < KTOP; ++i) {
            ull sup = (mlo[i] & klo) | (mhi[i] & khi);
            bool kp = (sv[i] > 0.f) && (sup == 0ull);
            if (kp) { if (i < 64) klo |= (1ull << i); else khi |= (1ull << (i - 64)); }
        }
        keeplo = klo; keephi = khi;
    }
    __syncthreads();

    if (tid < KTOP) {
        bool kp = (tid < 64) ? ((keeplo >> tid) & 1ull) : ((keephi >> (tid - 64)) & 1ull);
        size_t obase = (size_t)bc * KTOP + tid;
        nms_scores[obase] = kp ? sv[tid] : 0.f;
        float4 o; o.x = bx[tid][0]; o.y = bx[tid][1]; o.z = bx[tid][2]; o.w = bx[tid][3];
        reinterpret_cast<float4*>(nms_boxes)[obase] = o;
    }
}

// ---- pass 3: per-image final top-100 in ONE kernel (hist-cut fast path; exact slow path) ----
__global__ __launch_bounds__(256) void final_topk_kernel(const float* __restrict__ nms_scores,
                                                         const float* __restrict__ nms_boxes,
                                                         float* __restrict__ out) {
    int b = blockIdx.x;
    __shared__ ull arr[CAP2];                 // 16 KB
    __shared__ ull arr2[FPAD];                // 8 KB
    __shared__ uint hist[CBINS];
    __shared__ uint s_cut, s_mode, s_cnt2, s_nz;
    int tid = threadIdx.x;

    const float* srow = nms_scores + (size_t)b * NCAND;
    for (int i = tid; i < CBINS; i += 256) hist[i] = 0u;
    if (tid == 0) { s_cut = 0u; s_mode = 0u; s_cnt2 = 0u; s_nz = 0u; }
    __syncthreads();

    uint mynz = 0;
    for (int i = tid; i < NCAND; i += 256) {
        float s = srow[i];
        if (s > 0.f) {
            ++mynz;
            uint bits = __float_as_uint(s);
            uint bin = (bits - BASEBITS) >> CSHIFT;
            if (bin >= CBINS) bin = CBINS - 1;
            atomicAdd(&hist[bin], 1u);
        }
    }
    if (mynz) atomicAdd(&s_nz, mynz);
    __syncthreads();
    if (tid == 0) {
        if (s_nz >= (uint)KTOP) {
            uint cum = 0; int bb2 = 0;
            for (int i = CBINS - 1; i >= 0; --i) {
                cum += hist[i];
                if (cum >= (uint)KTOP) { bb2 = i; break; }
            }
            if (cum <= CAP2) { s_cut = BASEBITS + ((uint)bb2 << CSHIFT); s_mode = 1u; }
        }
    }
    __syncthreads();

    if (s_mode) {
        uint cutv = s_cut;
        for (int i = tid; i < NCAND; i += 256) {
            float s = srow[i];
            if (s > 0.f) {
                uint bits = __float_as_uint(s);
                if (bits >= cutv) {
                    uint p = atomicAdd(&s_cnt2, 1u);
                    arr[p] = (((ull)(~bits)) << 32) | (uint)i;
                }
            }
        }
        __syncthreads();
        int fcc = (int)s_cnt2;
        int FS = 1; while (FS < fcc) FS <<= 1; if (FS < 2) FS = 2;
        for (int i = fcc + tid; i < FS; i += 256) arr[i] = ~0ull;
        __syncthreads();
        bitonic_sort256(arr, FS, tid);
    } else {
        for (int ch = 0; ch < FCH; ++ch) {
            for (int i = tid; i < FPAD; i += 256) {
                ull key;
                if (i < FCHN) {
                    float s = srow[ch * FCHN + i];
                    uint bits = (s > 0.f) ? __float_as_uint(s) : 0u;
                    key = (((ull)(~bits)) << 32) | (uint)(ch * FCHN + i);
                } else key = ~0ull;
                arr2[i] = key;
            }
            __syncthreads();
            bitonic_sort256(arr2, FPAD, tid);
            if (tid < KTOP) arr[ch * KTOP + tid] = arr2[tid];
            __syncthreads();
        }
        for (int i = FCH * KTOP + tid; i < FPAD; i += 256) arr[i] = ~0ull;
        __syncthreads();
        bitonic_sort256(arr, FPAD, tid);
    }

    if (tid < MAXDET) {
        ull kk = arr[tid];
        uint hb = (uint)(kk >> 32);
        uint idx = (uint)(kk & 0xFFFFFFFFu);
        float val = __uint_as_float(~hb);     // zeros decode to 0.0f
        float4 b4 = reinterpret_cast<const float4*>(nms_boxes)[(size_t)b * NCAND + idx];
        reinterpret_cast<float4*>(out)[(size_t)b * MAXDET + tid] = b4;
        out[BB * MAXDET * 4 + b * MAXDET + tid] = val;
        out[BB * MAXDET * 5 + b * MAXDET + tid] = (float)(idx / KTOP + 1);
    }
}

extern "C" void kernel_launch(void* const* d_in, const int* in_sizes, int n_in,
                              void* d_out, int out_size, void* d_ws, size_t ws_size,
                              hipStream_t stream) {
    const float* loc    = (const float*)d_in[0];
    const float* conf   = (const float*)d_in[1];
    const float* priors = (const float*)d_in[2];
    float* out = (float*)d_out;

    // workspace layout (16B-aligned chunks); ccnt/ovf are the zeroed pair (contiguous)
    char* ws = (char*)d_ws;
    float* nms_scores = (float*)ws;                                        // 1.02 MB
    float* nms_boxes  = nms_scores + (size_t)BB * CM1 * KTOP;              // 4.1 MB
    ull*   cand       = (ull*)(nms_boxes + (size_t)BB * CM1 * KTOP * 4);   // 41.9 MB
    float2* mxs       = (float2*)(cand + (size_t)BB * CM1 * CAP2);         // 6.3 MB
    uint*  ccnt       = (uint*)(mxs + (size_t)BB * NN);                    // 2560 zeroed
    uint*  ovf        = ccnt + (size_t)BB * CM1;                           // 2560 zeroed

    zero_kernel<<<(BB * CM1 * 2 + 255) / 256, 256, 0, stream>>>(ccnt, BB * CM1 * 2);

    softmax_spec_kernel<<<BB * BPI, 256, 0, stream>>>(conf, mxs, cand, ccnt, ovf);
    nms_kernel<<<BB * CM1, 256, 0, stream>>>(cand, ccnt, ovf, conf, mxs, loc, priors,
                                             nms_scores, nms_boxes);
    final_topk_kernel<<<BB, 256, 0, stream>>>(nms_scores, nms_boxes, out);
}